// Round 18
// baseline (315.091 us; speedup 1.0000x reference)
//
#include <hip/hip_runtime.h>

using u16 = unsigned short;
using u32 = unsigned int;
typedef __attribute__((ext_vector_type(8))) short short8;
typedef __attribute__((ext_vector_type(4))) short s16x4;
typedef __attribute__((ext_vector_type(4))) float f32x4;
typedef __attribute__((ext_vector_type(2))) float f32x2;
typedef __attribute__((ext_vector_type(4))) u16 u16x4;
typedef __attribute__((ext_vector_type(4))) u32 u32x4;

constexpr int CB   = 4;
constexpr int CC   = 192;    // dim
constexpr int CN   = 16384;  // tokens per batch (128*128)
constexpr int BN   = CB * CN;
constexpr int CMLP = 384;

__device__ __forceinline__ float b2f(u16 u){ return __uint_as_float(((u32)u) << 16); }
__device__ __forceinline__ u16 f2b(float f){
  u32 u = __float_as_uint(f);
  u32 r = (u + 0x7FFFu + ((u >> 16) & 1u)) >> 16;
  return (u16)r;
}
// 8-byte-aligned load of 8 bf16
__device__ __forceinline__ short8 ld8(const u16* p) {
  s16x4 a = *(const s16x4*)p;
  s16x4 b = *(const s16x4*)(p + 4);
  short8 r;
  r[0]=a[0]; r[1]=a[1]; r[2]=a[2]; r[3]=a[3];
  r[4]=b[0]; r[5]=b[1]; r[6]=b[2]; r[7]=b[3];
  return r;
}
__device__ __forceinline__ u32 pk_bf16(float lo, float hi) {
  u32 r;
  asm("v_cvt_pk_bf16_f32 %0, %1, %2" : "=v"(r) : "v"(lo), "v"(hi));
  return r;
}
__device__ __forceinline__ float exp2_fast(float x) {
  float r;
  asm("v_exp_f32 %0, %1" : "=v"(r) : "v"(x));
  return r;
}
// async global -> LDS, 16 bytes/lane; LDS dest = wave-uniform base + lane*16
__device__ __forceinline__ void gl_lds16(const u16* g, u16* l) {
  __builtin_amdgcn_global_load_lds(
      (const __attribute__((address_space(1))) void*)(const void*)g,
      (__attribute__((address_space(3))) void*)(void*)l, 16, 0, 0);
}

// ---------------- LN (token-wise over C=192), src (B,C,N) f32 -> bf16 rows + fused
// cluster assignment (scores vs msnT + tie-exact argmax).
__global__ __launch_bounds__(256) void ln_k(const float* __restrict__ src,
    const float* __restrict__ gg, const float* __restrict__ bb, u16* __restrict__ out,
    const u16* __restrict__ msnT, int* __restrict__ belong)
{
  __shared__ float t[64 * 193];
  __shared__ float sg[192], sb[192];
  __shared__ float smu[64], srs[64];
  const int tid = threadIdx.x;
  const int blk = blockIdx.x;
  const int b = blk >> 8;
  const int n0 = (blk & 255) * 64;
  if (tid < 192) { sg[tid] = gg[tid]; sb[tid] = bb[tid]; }
  const size_t sbase = ((size_t)b * CC) * CN + n0;
  #pragma unroll
  for (int it = 0; it < 48; ++it) {
    int c = it * 4 + (tid >> 6);
    int tok = tid & 63;
    t[tok * 193 + c] = src[sbase + (size_t)c * CN + tok];
  }
  __syncthreads();
  {
    int tok = tid >> 2, sub = tid & 3;
    float s = 0.f, sq = 0.f;
    #pragma unroll
    for (int i = 0; i < 48; ++i) {
      float v = t[tok * 193 + sub * 48 + i];
      s += v; sq += v * v;
    }
    s  += __shfl_xor(s, 1);  s  += __shfl_xor(s, 2);
    sq += __shfl_xor(sq, 1); sq += __shfl_xor(sq, 2);
    float mu = s * (1.f / 192.f);
    float var = fmaxf(sq * (1.f / 192.f) - mu * mu, 0.f);
    float rs = rsqrtf(var + 1e-5f);
    if (sub == 0) { smu[tok] = mu; srs[tok] = rs; }
  }
  __syncthreads();
  const size_t obase = ((size_t)(b * CN + n0)) * CC;
  #pragma unroll
  for (int it = 0; it < 48; ++it) {
    int e = it * 256 + tid;
    int tk = e / 192, c = e % 192;
    float v = (t[tk * 193 + c] - smu[tk]) * srs[tk] * sg[c] + sb[c];
    out[obase + (size_t)tk * CC + c] = f2b(v);
  }

  {
    const int wv = tid >> 6, lane = tid & 63;
    const int l15 = lane & 15, g4 = lane >> 4, q8 = g4 * 8;
    const int tok = wv * 16 + l15;
    const float mu = smu[tok], rs = srs[tok];
    short8 afm[6];
    #pragma unroll
    for (int ks = 0; ks < 6; ++ks) {
      u32x4 qq;
      #pragma unroll
      for (int j = 0; j < 4; ++j) {
        int c = ks * 32 + q8 + 2 * j;
        float v0 = (t[tok * 193 + c]     - mu) * rs * sg[c]     + sb[c];
        float v1 = (t[tok * 193 + c + 1] - mu) * rs * sg[c + 1] + sb[c + 1];
        qq[j] = pk_bf16(v0, v1);
      }
      afm[ks] = __builtin_bit_cast(short8, qq);
    }
    f32x4 sacc[4];
    #pragma unroll
    for (int ct = 0; ct < 4; ++ct) {
      sacc[ct] = 0.f;
      const u16* pM = msnT + (ct * 16 + l15) * 192 + q8;
      short8 mf[6];
      #pragma unroll
      for (int ks = 0; ks < 6; ++ks) mf[ks] = *(const short8*)(pM + ks * 32);
      #pragma unroll
      for (int ks = 0; ks < 6; ++ks)
        sacc[ct] = __builtin_amdgcn_mfma_f32_16x16x32_bf16(afm[ks], mf[ks], sacc[ct], 0, 0, 0);
    }
    #pragma unroll
    for (int r = 0; r < 4; ++r) {
      float bv = -3e38f; int bi = 1 << 30;
      #pragma unroll
      for (int ct = 0; ct < 4; ++ct) {
        float v = sacc[ct][r];
        int ci = ct * 16 + l15;
        if (v > bv || (v == bv && ci < bi)) { bv = v; bi = ci; }
      }
      #pragma unroll
      for (int d = 1; d < 16; d <<= 1) {
        float ov = __shfl_xor(bv, d);
        int   oi = __shfl_xor(bi, d);
        if (ov > bv || (ov == bv && oi < bi)) { bv = ov; bi = oi; }
      }
      if (l15 == 0) belong[b * CN + n0 + wv * 16 + g4 * 4 + r] = bi;
    }
  }
}

// ---------------- QKV GEMM: Q (scaled by QSC) -> qo token-order [BN][192];
// K,V -> kv SORTED order [BN][384] via inv scatter (contiguous 768B row writes).
__global__ __launch_bounds__(256) void gemmQ_k(const u16* __restrict__ A,
    const u16* __restrict__ Wt, const int* __restrict__ inv,
    u16* __restrict__ qo, u16* __restrict__ kv)
{
  __shared__ __attribute__((aligned(16))) u16 lA[64 * 192];
  __shared__ int sInv[64];
  const float QSC = 0.20412414523193154f * 1.4426950408889634f;
  const int tid = threadIdx.x;
  const int row0 = blockIdx.x * 64;
  const int b = row0 >> 14;
  const int wv = tid >> 6, lane = tid & 63;
  const int l15 = lane & 15, g4 = lane >> 4, q8 = g4 * 8;
  const int colw = wv * 144;

  if (tid < 64) sInv[tid] = inv[row0 + tid];
  #pragma unroll
  for (int j = 0; j < 6; ++j) {
    int C = (wv * 6 + j) * 64 + lane;
    int r = C / 24;
    int c = C - r * 24;
    gl_lds16(A + (size_t)(row0 + r) * 192 + c * 8, lA + (wv * 6 + j) * 512);
  }
  __syncthreads();
  short8 af[4][6];
  #pragma unroll
  for (int rt = 0; rt < 4; ++rt)
    #pragma unroll
    for (int ks = 0; ks < 6; ++ks)
      af[rt][ks] = *(const short8*)(lA + (rt * 16 + l15) * 192 + ks * 32 + q8);

  const size_t kvb = (size_t)b * CN * 384;
  #pragma unroll
  for (int jc = 0; jc < 9; ++jc) {
    const u16* pW = Wt + (size_t)(colw + jc * 16 + l15) * 192 + q8;
    short8 wf[6];
    #pragma unroll
    for (int ks = 0; ks < 6; ++ks) wf[ks] = *(const short8*)(pW + ks * 32);
    f32x4 acc[4];
    #pragma unroll
    for (int rt = 0; rt < 4; ++rt) acc[rt] = 0.f;
    #pragma unroll
    for (int ks = 0; ks < 6; ++ks)
      #pragma unroll
      for (int rt = 0; rt < 4; ++rt)
        acc[rt] = __builtin_amdgcn_mfma_f32_16x16x32_bf16(af[rt][ks], wf[ks], acc[rt], 0, 0, 0);
    int col = colw + jc * 16 + l15;
    if (colw + jc * 16 < 192) {
      // Q columns, pre-scaled, token order
      #pragma unroll
      for (int rt = 0; rt < 4; ++rt) {
        int row = row0 + rt * 16 + g4 * 4;
        #pragma unroll
        for (int r = 0; r < 4; ++r)
          qo[(size_t)(row + r) * 192 + col] = f2b(acc[rt][r] * QSC);
      }
    } else {
      // K/V columns, scattered to sorted position
      #pragma unroll
      for (int rt = 0; rt < 4; ++rt) {
        int rloc = rt * 16 + g4 * 4;
        #pragma unroll
        for (int r = 0; r < 4; ++r) {
          int pos = sInv[rloc + r];
          kv[kvb + (size_t)pos * 384 + (col - 192)] = f2b(acc[rt][r]);
        }
      }
    }
  }
}

// ---------------- prep: normalized means (bf16, [64][192]) + kg/vg ([h][64][24] f32)
__global__ __launch_bounds__(192) void prep_means_k(const float* __restrict__ means,
    const float* __restrict__ Wkg, const float* __restrict__ Wvg,
    u16* __restrict__ msnT, float* __restrict__ kg, float* __restrict__ vg)
{
  __shared__ float sv[192];
  __shared__ float red[192];
  const int m = blockIdx.x, c = threadIdx.x;
  float v = means[m * 192 + c];
  sv[c] = v; red[c] = v * v;
  __syncthreads();
  for (int s = 96; s >= 3; s >>= 1) {
    if (c < s) red[c] += red[c + s];
    __syncthreads();
  }
  if (c == 0) red[0] = 1.f / (sqrtf(red[0] + red[1] + red[2]) + 1e-12f);
  __syncthreads();
  float scale = red[0];
  msnT[m * 192 + c] = f2b(v * scale);
  float a1 = 0.f, a2 = 0.f;
  for (int cc = 0; cc < 192; ++cc) {
    float mv = sv[cc];
    a1 += mv * Wkg[cc * 192 + c];
    a2 += mv * Wvg[cc * 192 + c];
  }
  int h = c / 24, d = c % 24;
  kg[h * (64 * 24) + m * 24 + d] = a1;
  vg[h * (64 * 24) + m * 24 + d] = a2;
}

// ---------------- merged weight prep
__global__ __launch_bounds__(256) void wprep_k(
    const float* __restrict__ Wp, const float* __restrict__ Wc, u16* __restrict__ WpcT,
    const float* __restrict__ Wq, const float* __restrict__ Wk, const float* __restrict__ Wv,
    u16* __restrict__ WqkvT,
    const float* __restrict__ Wfc1, u16* __restrict__ Wfc1T,
    const float* __restrict__ Wfc2, u16* __restrict__ Wfc2T)
{
  int blk = blockIdx.x;
  int tid = threadIdx.x;
  if (blk < 144) {
    int e = blk * 256 + tid;
    if (e < 192 * 192) {
      int i = e / 192, j = e % 192;
      float a = 0.f;
      for (int k = 0; k < 192; ++k) a += Wp[i * 192 + k] * Wc[k * 192 + j];
      WpcT[j * 192 + i] = f2b(a);
    }
    return;
  }
  blk -= 144;
  if (blk < 432) {
    int which = blk / 144;
    int e = (blk % 144) * 256 + tid;
    const float* W = (which == 0) ? Wq : (which == 1) ? Wk : Wv;
    if (e < 192 * 192) {
      int j = e / 192, k = e % 192;
      WqkvT[which * 192 * 192 + e] = f2b(W[k * 192 + j]);
    }
    return;
  }
  blk -= 432;
  if (blk < 288) {
    int e = blk * 256 + tid;
    if (e < 192 * 384) {
      int j = e / 192, k = e % 192;
      Wfc1T[e] = f2b(Wfc1[k * 384 + j]);
    }
    return;
  }
  blk -= 288;
  {
    int e = blk * 256 + tid;
    if (e < 384 * 192) {
      int j = e / 384, k = e % 384;
      Wfc2T[e] = f2b(Wfc2[k * 192 + j]);
    }
  }
}

// ---------------- fused RESID(proj+residual) + MLP-LN + fc1 GEMM. A = qo rows (dense 384B).
__global__ __launch_bounds__(256) void resid_k(const u16* __restrict__ qo,
    const u16* __restrict__ WpcT, const float* __restrict__ x, u16* __restrict__ xt2,
    const float* __restrict__ g2, const float* __restrict__ b2,
    const u16* __restrict__ Wfc1T, u16* __restrict__ h1)
{
  __shared__ __attribute__((aligned(16))) u16 shraw[64 * 200];  // lA alias lnb16
  __shared__ float smu2[64], srs2[64];
  u16* lA    = shraw;
  u16* lnb16 = shraw;
  const int tid = threadIdx.x;
  const int row0 = blockIdx.x * 64;
  const int b = row0 >> 14;
  const int wv = tid >> 6, lane = tid & 63;
  const int l15 = lane & 15, g4 = lane >> 4, q8 = g4 * 8;

  #pragma unroll
  for (int j = 0; j < 6; ++j) {
    int C = (wv * 6 + j) * 64 + lane;
    int r = C / 24;
    int c = C - r * 24;
    const u16* gp = qo + (size_t)(row0 + r) * 192 + c * 8;
    gl_lds16(gp, lA + (wv * 6 + j) * 512);
  }
  __syncthreads();
  short8 af[4][6];
  #pragma unroll
  for (int rt = 0; rt < 4; ++rt)
    #pragma unroll
    for (int ks = 0; ks < 6; ++ks)
      af[rt][ks] = *(const short8*)(lA + (rt * 16 + l15) * 192 + ks * 32 + q8);
  __syncthreads();

  const int colw = wv * 48;
  #pragma unroll
  for (int jc = 0; jc < 3; ++jc) {
    const u16* pW = WpcT + (size_t)(colw + jc * 16 + l15) * 192 + q8;
    short8 wf[6];
    #pragma unroll
    for (int ks = 0; ks < 6; ++ks) wf[ks] = *(const short8*)(pW + ks * 32);
    f32x4 acc[4];
    #pragma unroll
    for (int rt = 0; rt < 4; ++rt) acc[rt] = 0.f;
    #pragma unroll
    for (int ks = 0; ks < 6; ++ks)
      #pragma unroll
      for (int rt = 0; rt < 4; ++rt)
        acc[rt] = __builtin_amdgcn_mfma_f32_16x16x32_bf16(wf[ks], af[rt][ks], acc[rt], 0, 0, 0);
    #pragma unroll
    for (int rt = 0; rt < 4; ++rt) {
      int n = ((row0 + rt * 16) & 16383) + l15;
      #pragma unroll
      for (int r = 0; r < 4; ++r) {
        int col = colw + jc * 16 + g4 * 4 + r;
        size_t o2 = ((size_t)(b * CC + col)) * CN + n;
        float val = x[o2] + acc[rt][r];
        u16 vb = f2b(val);
        xt2[o2] = vb;
        lnb16[(rt * 16 + l15) * 200 + col] = vb;
      }
    }
  }
  __syncthreads();

  {
    int tok = tid >> 2, sub = tid & 3;
    float s = 0.f, sq = 0.f;
    #pragma unroll
    for (int i = 0; i < 48; ++i) {
      float v = b2f(lnb16[tok * 200 + sub * 48 + i]);
      s += v; sq += v * v;
    }
    s  += __shfl_xor(s, 1);  s  += __shfl_xor(s, 2);
    sq += __shfl_xor(sq, 1); sq += __shfl_xor(sq, 2);
    float mu = s * (1.f / 192.f);
    float var = fmaxf(sq * (1.f / 192.f) - mu * mu, 0.f);
    float rs = rsqrtf(var + 1e-5f);
    if (sub == 0) { smu2[tok] = mu; srs2[tok] = rs; }
  }
  __syncthreads();
  #pragma unroll
  for (int it = 0; it < 48; ++it) {
    int e = it * 256 + tid;
    int tk = e / 192, c = e % 192;
    float v = (b2f(lnb16[tk * 200 + c]) - smu2[tk]) * srs2[tk] * g2[c] + b2[c];
    lnb16[tk * 200 + c] = f2b(v);
  }
  __syncthreads();

  short8 af2[4][6];
  #pragma unroll
  for (int rt = 0; rt < 4; ++rt)
    #pragma unroll
    for (int ks = 0; ks < 6; ++ks)
      af2[rt][ks] = *(const short8*)(lnb16 + (rt * 16 + l15) * 200 + ks * 32 + q8);
  const int colw2 = wv * 96;
  #pragma unroll
  for (int jc = 0; jc < 6; ++jc) {
    const u16* pW = Wfc1T + (size_t)(colw2 + jc * 16 + l15) * 192 + q8;
    short8 wf[6];
    #pragma unroll
    for (int ks = 0; ks < 6; ++ks) wf[ks] = *(const short8*)(pW + ks * 32);
    f32x4 acc[4];
    #pragma unroll
    for (int rt = 0; rt < 4; ++rt) acc[rt] = 0.f;
    #pragma unroll
    for (int ks = 0; ks < 6; ++ks)
      #pragma unroll
      for (int rt = 0; rt < 4; ++rt)
        acc[rt] = __builtin_amdgcn_mfma_f32_16x16x32_bf16(af2[rt][ks], wf[ks], acc[rt], 0, 0, 0);
    int col = colw2 + jc * 16 + l15;
    #pragma unroll
    for (int rt = 0; rt < 4; ++rt) {
      int row = row0 + rt * 16 + g4 * 4;
      #pragma unroll
      for (int r = 0; r < 4; ++r)
        h1[(size_t)(row + r) * CMLP + col] = f2b(acc[rt][r]);
    }
  }
}

// ---------------- FINAL GEMM: h2g rows -> out (B,C,N) f32 + xt2 resid.
template<int KTOT, int NCOLS>
__global__ __launch_bounds__(256) void gemmF_k(const u16* __restrict__ A,
    const u16* __restrict__ Wt, const u16* __restrict__ resid,
    float* __restrict__ o, int astride)
{
  __shared__ __attribute__((aligned(16))) u16 lA[64 * 192];
  constexpr int KC = KTOT / 192;
  constexpr int WCOLS = NCOLS / 4;
  constexpr int WCT = WCOLS / 16;
  const int tid = threadIdx.x;
  const int row0 = blockIdx.x * 64;
  const int b = row0 >> 14;
  const int wv = tid >> 6, lane = tid & 63;
  const int l15 = lane & 15, g4 = lane >> 4, q8 = g4 * 8;
  const int colw = wv * WCOLS;

  f32x4 acc[WCT * 4];
  #pragma unroll
  for (int i = 0; i < WCT * 4; ++i) acc[i] = 0.f;

  #pragma unroll
  for (int kc = 0; kc < KC; ++kc) {
    if (kc) __syncthreads();
    #pragma unroll
    for (int j = 0; j < 6; ++j) {
      int C = (wv * 6 + j) * 64 + lane;
      int r = C / 24;
      int c = C - r * 24;
      const u16* gp = A + (size_t)(row0 + r) * astride + kc * 192 + c * 8;
      gl_lds16(gp, lA + (wv * 6 + j) * 512);
    }
    __syncthreads();
    short8 af[4][6];
    #pragma unroll
    for (int rt = 0; rt < 4; ++rt)
      #pragma unroll
      for (int ks = 0; ks < 6; ++ks)
        af[rt][ks] = *(const short8*)(lA + (rt * 16 + l15) * 192 + ks * 32 + q8);

    #pragma unroll
    for (int jc = 0; jc < WCT; ++jc) {
      const u16* pW = Wt + (size_t)(colw + jc * 16 + l15) * KTOT + kc * 192 + q8;
      short8 wf[6];
      #pragma unroll
      for (int ks = 0; ks < 6; ++ks) wf[ks] = *(const short8*)(pW + ks * 32);
      #pragma unroll
      for (int ks = 0; ks < 6; ++ks)
        #pragma unroll
        for (int rt = 0; rt < 4; ++rt)
          acc[jc * 4 + rt] = __builtin_amdgcn_mfma_f32_16x16x32_bf16(wf[ks], af[rt][ks], acc[jc * 4 + rt], 0, 0, 0);
    }
  }
  #pragma unroll
  for (int jc = 0; jc < WCT; ++jc)
    #pragma unroll
    for (int tt = 0; tt < 4; ++tt) {
      int n = ((row0 + tt * 16) & 16383) + l15;
      #pragma unroll
      for (int r = 0; r < 4; ++r) {
        int outcol = colw + jc * 16 + g4 * 4 + r;
        size_t o2 = ((size_t)(b * CC + outcol)) * CN + n;
        o[o2] = b2f(resid[o2]) + acc[jc * 4 + tt][r];
      }
    }
}

// ---------------- stable counting sort: hist -> scan -> rank/scatter (idx + inv)
__global__ __launch_bounds__(256) void hist_k(const int* __restrict__ belong, int* __restrict__ histG)
{
  __shared__ int h[64];
  int tid = threadIdx.x, blk = blockIdx.x;
  if (tid < 64) h[tid] = 0;
  __syncthreads();
  int c = belong[blk * 256 + tid];
  atomicAdd(&h[c], 1);
  __syncthreads();
  if (tid < 64) histG[blk * 64 + tid] = h[tid];
}

__global__ __launch_bounds__(64) void scan_k(const int* __restrict__ histG, int* __restrict__ chunkBase)
{
  int b = blockIdx.x, c = threadIdx.x;
  int tot = 0;
  for (int ch = 0; ch < 64; ++ch) tot += histG[(b * 64 + ch) * 64 + c];
  int inc = tot;
  for (int d = 1; d < 64; d <<= 1) {
    int v = __shfl_up(inc, d);
    if (c >= d) inc += v;
  }
  int run = inc - tot;
  for (int ch = 0; ch < 64; ++ch) {
    chunkBase[(b * 64 + ch) * 64 + c] = run;
    run += histG[(b * 64 + ch) * 64 + c];
  }
}

__global__ __launch_bounds__(256) void rank_k(const int* __restrict__ belong,
    const int* __restrict__ chunkBase, int* __restrict__ idx, int* __restrict__ inv)
{
  __shared__ int WH[4][64];
  int tid = threadIdx.x, blk = blockIdx.x;
  int b = blk >> 6, chl = blk & 63;
  int wv = tid >> 6, lane = tid & 63;
  ((int*)WH)[tid] = 0;
  __syncthreads();
  int nl = chl * 256 + tid;
  int c = belong[blk * 256 + tid];
  int rank = 0;
  for (int m = 0; m < 64; ++m) {
    unsigned long long msk = __ballot(c == m);
    if (c == m) {
      rank = __popcll(msk & ((1ull << lane) - 1ull));
      if (rank == 0) WH[wv][m] = __popcll(msk);
    }
  }
  __syncthreads();
  int off = 0;
  #pragma unroll
  for (int w = 0; w < 3; ++w) if (w < wv) off += WH[w][c];
  int pos = chunkBase[(b * 64 + chl) * 64 + c] + off + rank;
  idx[b * CN + pos] = nl;
  inv[b * CN + nl] = pos;
}

// ---------------- MFMA flash attention: K/V now PRE-SORTED in kv -> sequential DMA
// staging (position index, reflected tail inline). Q gathered from qo (pre-scaled);
// O written token-order into qo. Math identical to R17.
__global__ __launch_bounds__(256) void attn_k(u16* __restrict__ qo,
    const u16* __restrict__ kv,
    const float* __restrict__ kg, const float* __restrict__ vg,
    const int* __restrict__ idx)
{
  __shared__ __attribute__((aligned(16))) u16 sK[320 * 24];
  __shared__ __attribute__((aligned(16))) u16 sVT[25 * 332];  // row 24 = ones
  __shared__ u16 sidx[256];
  const int g = blockIdx.x, h = blockIdx.y, b = blockIdx.z;
  const int tid = threadIdx.x;
  const int wave = tid >> 6, lane = tid & 63;
  const int l15 = lane & 15, g4 = lane >> 4;
  const int q8 = g4 * 8;
  const size_t qob = (size_t)b * CN * 192;
  const size_t kvb = (size_t)b * CN * 384;
  short8 z8 = {0,0,0,0,0,0,0,0};

  {
    int p = g * 128 + tid;
    if (p >= CN) p = 2 * CN - 1 - p;
    sidx[tid] = (u16)idx[b * CN + p];
  }
  for (int e = tid; e < 332; e += 256) sVT[24 * 332 + e] = 0x3F80;
  __syncthreads();

  // window K rows 0..255: SEQUENTIAL DMA from sorted kv (3 x 16B chunks per 48B slice)
  #pragma unroll
  for (int it = 0; it < 3; ++it) {
    int C = (it * 4 + wave) * 64 + lane;   // chunk id 0..767
    int r = C / 3, cs = C - r * 3;
    int p = g * 128 + r;
    if (p >= CN) p = 2 * CN - 1 - p;
    gl_lds16(kv + kvb + (size_t)p * 384 + h * 24 + cs * 8,
             sK + (it * 4 + wave) * 512);
  }
  // dict K rows 256..319 (f32 -> bf16 convert)
  #pragma unroll
  for (int it = 0; it < 2; ++it) {
    int e4 = (it * 256 + tid) * 4;
    if (e4 < 1536) {
      int r = e4 / 24, c = e4 % 24;
      const float* kp = kg + h * 1536 + r * 24 + c;
      u16x4 o;
      o[0] = f2b(kp[0]); o[1] = f2b(kp[1]); o[2] = f2b(kp[2]); o[3] = f2b(kp[3]);
      *(u16x4*)(sK + (256 + r) * 24 + c) = o;
    }
  }
  // V^T staging from sorted kv (transposed writes; sequential global reads)
  #pragma unroll
  for (int it = 0; it < 8; ++it) {
    int e4 = (it * 256 + tid) * 4;
    if (e4 < 7680) {
      int kk = e4 / 24, c = e4 % 24;
      if (kk < 256) {
        int p = g * 128 + kk;
        if (p >= CN) p = 2 * CN - 1 - p;
        u16x4 v = *(const u16x4*)(kv + kvb + (size_t)p * 384 + 192 + h * 24 + c);
        sVT[(c + 0) * 332 + kk] = v[0];
        sVT[(c + 1) * 332 + kk] = v[1];
        sVT[(c + 2) * 332 + kk] = v[2];
        sVT[(c + 3) * 332 + kk] = v[3];
      } else {
        const float* vp = vg + h * 1536 + (kk - 256) * 24 + c;
        sVT[(c + 0) * 332 + kk] = f2b(vp[0]);
        sVT[(c + 1) * 332 + kk] = f2b(vp[1]);
        sVT[(c + 2) * 332 + kk] = f2b(vp[2]);
        sVT[(c + 3) * 332 + kk] = f2b(vp[3]);
      }
    }
  }

  // Q B-frags gathered from qo (pre-scaled in gemmQ)
  short8 qf[2];
  #pragma unroll
  for (int rt = 0; rt < 2; ++rt) {
    int qrow = sidx[wave * 32 + rt * 16 + l15];
    qf[rt] = (g4 < 3) ? ld8(qo + qob + (size_t)qrow * 192 + h * 24 + q8) : z8;
  }
  __syncthreads();

  f32x4 O1[2][2], O2[2][2];
  #pragma unroll
  for (int rt = 0; rt < 2; ++rt)
    #pragma unroll
    for (int ct2 = 0; ct2 < 2; ++ct2) { O1[rt][ct2] = 0.f; O2[rt][ct2] = 0.f; }

  const int srcLo = ((lane & 16) << 1) + l15;
  const int srcHi = srcLo + 16;
  const bool hiSel = lane >= 32;
  f32x4 zz = 0.f;

  auto do_tile = [&](int ktile, f32x4 (*O)[2]) {
    short8 aK[4];
    #pragma unroll
    for (int ct = 0; ct < 4; ++ct)
      aK[ct] = (g4 < 3) ? ld8(sK + (ktile + ct * 16 + l15) * 24 + q8) : z8;
    short8 bV[2][2];
    #pragma unroll
    for (int kc = 0; kc < 2; ++kc)
      #pragma unroll
      for (int ct2 = 0; ct2 < 2; ++ct2) {
        int vrow = ct2 * 16 + l15;
        bV[kc][ct2] = (vrow < 25) ? ld8(sVT + vrow * 332 + ktile + kc * 32 + q8) : z8;
      }
    #pragma unroll
    for (int rt = 0; rt < 2; ++rt) {
      f32x4 p[4];
      __builtin_amdgcn_s_setprio(1);
      #pragma unroll
      for (int ct = 0; ct < 4; ++ct)
        p[ct] = __builtin_amdgcn_mfma_f32_16x16x32_bf16(aK[ct], qf[rt], zz, 0, 0, 0);
      __builtin_amdgcn_s_setprio(0);
      #pragma unroll
      for (int ct = 0; ct < 4; ++ct)
        #pragma unroll
        for (int r = 0; r < 4; ++r)
          p[ct][r] = exp2_fast(p[ct][r]);
      #pragma unroll
      for (int kc = 0; kc < 2; ++kc) {
        u32 wA0 = pk_bf16(p[kc * 2][0], p[kc * 2][1]);
        u32 wA1 = pk_bf16(p[kc * 2][2], p[kc * 2][3]);
        u32 wB0 = pk_bf16(p[kc * 2 + 1][0], p[kc * 2 + 1][1]);
        u32 wB1 = pk_bf16(p[kc * 2 + 1][2], p[kc * 2 + 1][3]);
        u32 a0 = (u32)__shfl((int)wA0, srcLo), a1 = (u32)__shfl((int)wA1, srcLo);
        u32 a2 = (u32)__shfl((int)wA0, srcHi), a3 = (u32)__shfl((int)wA1, srcHi);
        u32 b0 = (u32)__shfl((int)wB0, srcLo), b1 = (u32)__shfl((int)wB1, srcLo);
        u32 b2 = (u32)__shfl((int)wB0, srcHi), b3 = (u32)__shfl((int)wB1, srcHi);
        u32x4 fr;
        fr[0] = hiSel ? b0 : a0; fr[1] = hiSel ? b1 : a1;
        fr[2] = hiSel ? b2 : a2; fr[3] = hiSel ? b3 : a3;
        short8 aP = __builtin_bit_cast(short8, fr);
        __builtin_amdgcn_s_setprio(1);
        #pragma unroll
        for (int ct2 = 0; ct2 < 2; ++ct2)
          O[rt][ct2] = __builtin_amdgcn_mfma_f32_16x16x32_bf16(aP, bV[kc][ct2], O[rt][ct2], 0, 0, 0);
        __builtin_amdgcn_s_setprio(0);
      }
    }
  };

  do_tile(0,   O1);
  do_tile(64,  O1);
  do_tile(128, O1);
  do_tile(192, O1);
  do_tile(256, O2);

  const int lsrc = (lane & 48) + 8;
  #pragma unroll
  for (int rt = 0; rt < 2; ++rt) {
    #pragma unroll
    for (int r = 0; r < 4; ++r) {
      float s1 = __shfl(O1[rt][1][r], lsrc);
      float s2 = __shfl(O2[rt][1][r], lsrc);
      float i1 = 1.f / s1;
      float i2 = 1.f / s2;
      int tok = sidx[wave * 32 + rt * 16 + g4 * 4 + r];
      #pragma unroll
      for (int ct2 = 0; ct2 < 2; ++ct2) {
        int d = ct2 * 16 + l15;
        if (d < 24) {
          float v = O1[rt][ct2][r] * i1 + O2[rt][ct2][r] * i2;
          qo[qob + (size_t)tok * 192 + h * 24 + d] = f2b(v);
        }
      }
    }
  }
}

// ---------------- depthwise 3x3 + GELU, token-major (B,N,384), 8 channels per block.
__global__ __launch_bounds__(256) void conv_k(const u16* __restrict__ h1,
    const float* __restrict__ dw, u16* __restrict__ h2g)
{
  __shared__ float t[1156 * 10];
  __shared__ float sdw[72];
  const int tile = blockIdx.x;
  const int jg = blockIdx.y;
  const int bb = blockIdx.z;
  const int y0 = (tile >> 2) * 32, x0 = (tile & 3) * 32;
  const int tid = threadIdx.x;
  if (tid < 72) sdw[tid] = dw[jg * 72 + tid];
  #pragma unroll
  for (int it = 0; it < 5; ++it) {
    int e = it * 256 + tid;
    if (e < 1156) {
      int yy = e / 34 - 1 + y0, xx = e % 34 - 1 + x0;
      float v[8];
      if (yy >= 0 && yy < 128 && xx >= 0 && xx < 128) {
        short8 raw = *(const short8*)(h1 + ((size_t)(bb * CN + yy * 128 + xx)) * CMLP + jg * 8);
        #pragma unroll
        for (int c = 0; c < 8; ++c) v[c] = b2f((u16)raw[c]);
      } else {
        #pragma unroll
        for (int c = 0; c < 8; ++c) v[c] = 0.f;
      }
      #pragma unroll
      for (int c = 0; c < 8; c += 2) {
        f32x2 p; p[0] = v[c]; p[1] = v[c + 1];
        *(f32x2*)(t + e * 10 + c) = p;
      }
    }
  }
  __syncthreads();
  float acc[4][8];
  #pragma unroll
  for (int px = 0; px < 4; ++px)
    #pragma unroll
    for (int c = 0; c < 8; ++c) acc[px][c] = 0.f;
  #pragma unroll
  for (int k = 0; k < 9; ++k) {
    const int dy = k / 3, dx = k % 3;
    float w[8];
    #pragma unroll
    for (int c = 0; c < 8; ++c) w[c] = sdw[c * 9 + k];
    #pragma unroll
    for (int px = 0; px < 4; ++px) {
      int idx2 = px * 256 + tid;
      int oy = idx2 >> 5, ox = idx2 & 31;
      const float* vp = t + ((oy + dy) * 34 + ox + dx) * 10;
      #pragma unroll
      for (int c = 0; c < 8; ++c) acc[px][c] += vp[c] * w[c];
    }
  }
  #pragma unroll
  for (int px = 0; px < 4; ++px) {
    int idx2 = px * 256 + tid;
    int oy = idx2 >> 5, ox = idx2 & 31;
    short8 o;
    #pragma unroll
    for (int c = 0; c < 8; ++c) {
      float a = acc[px][c];
      float u = 1.5957691216057308f * (a + 0.044715f * a * a * a);
      float gel = a / (1.f + __expf(-u));
      o[c] = (short)f2b(gel);
    }
    *(short8*)(h2g + ((size_t)(bb * CN + (y0 + oy) * 128 + x0 + ox)) * CMLP + jg * 8) = o;
  }
}

extern "C" void kernel_launch(void* const* d_in, const int* in_sizes, int n_in,
                              void* d_out, int out_size, void* d_ws, size_t ws_size,
                              hipStream_t stream)
{
  const float* x     = (const float*)d_in[0];
  const float* ln_g  = (const float*)d_in[1];
  const float* ln_b  = (const float*)d_in[2];
  const float* Wq    = (const float*)d_in[3];
  const float* Wk    = (const float*)d_in[4];
  const float* Wv    = (const float*)d_in[5];
  const float* Wproj = (const float*)d_in[6];
  const float* Wkg   = (const float*)d_in[7];
  const float* Wvg   = (const float*)d_in[8];
  const float* means = (const float*)d_in[9];
  const float* Wconv = (const float*)d_in[10];
  const float* mlp_g = (const float*)d_in[11];
  const float* mlp_b = (const float*)d_in[12];
  const float* Wfc1  = (const float*)d_in[13];
  const float* dw    = (const float*)d_in[14];
  const float* Wfc2  = (const float*)d_in[15];
  float* out = (float*)d_out;
  (void)in_sizes; (void)n_in; (void)out_size; (void)ws_size;

  char* ws = (char*)d_ws;
  size_t off = 0;
  auto alloc = [&](size_t sz) { void* p = ws + off; off += (sz + 255) & ~(size_t)255; return p; };
  u16*  xn    = (u16*)alloc((size_t)BN * 192 * 2);
  u16*  qo    = (u16*)alloc((size_t)BN * 192 * 2);   // Q (scaled) / O, token order
  u16*  kvb   = (u16*)alloc((size_t)BN * 384 * 2);   // K+V, SORTED order
  u16*  xt2   = (u16*)alloc((size_t)BN * 192 * 2);   // channel-major (B,C,N) bf16
  u16*  h1    = (u16*)alloc((size_t)BN * 384 * 2);   // (B,N,384)
  u16*  h2g   = (u16*)alloc((size_t)BN * 384 * 2);   // (B,N,384)
  u16*  msnT  = (u16*)alloc(64 * 192 * 2);
  u16*  WqkvT = (u16*)alloc(576 * 192 * 2);
  u16*  WpcT  = (u16*)alloc(192 * 192 * 2);
  u16*  Wfc1T = (u16*)alloc(384 * 192 * 2);
  u16*  Wfc2T = (u16*)alloc(192 * 384 * 2);
  float* kg   = (float*)alloc(8 * 64 * 24 * 4);
  float* vg   = (float*)alloc(8 * 64 * 24 * 4);
  int*  belong = (int*)alloc(BN * 4);
  int*  idxb   = (int*)alloc(BN * 4);
  int*  invb   = (int*)alloc(BN * 4);
  int*  histG  = (int*)alloc(256 * 64 * 4);
  int*  chunkBase = (int*)alloc(256 * 64 * 4);

  prep_means_k<<<64, 192, 0, stream>>>(means, Wkg, Wvg, msnT, kg, vg);
  wprep_k<<<1152, 256, 0, stream>>>(Wproj, Wconv, WpcT, Wq, Wk, Wv, WqkvT,
                                    Wfc1, Wfc1T, Wfc2, Wfc2T);

  ln_k<<<1024, 256, 0, stream>>>(x, ln_g, ln_b, xn, msnT, belong);
  hist_k<<<256, 256, 0, stream>>>(belong, histG);
  scan_k<<<4, 64, 0, stream>>>(histG, chunkBase);
  rank_k<<<256, 256, 0, stream>>>(belong, chunkBase, idxb, invb);
  gemmQ_k<<<1024, 256, 0, stream>>>(xn, WqkvT, invb, qo, kvb);
  attn_k<<<dim3(128, 8, 4), 256, 0, stream>>>(qo, kvb, kg, vg, idxb);
  resid_k<<<1024, 256, 0, stream>>>(qo, WpcT, x, xt2, mlp_g, mlp_b, Wfc1T, h1);
  conv_k<<<dim3(16, 48, 4), 256, 0, stream>>>(h1, dw, h2g);
  gemmF_k<384, 192><<<1024, 256, 0, stream>>>(h2g, Wfc2T, xt2, out, 384);
}

// Round 19
// 303.519 us; speedup vs baseline: 1.0381x; 1.0381x over previous
//
#include <hip/hip_runtime.h>

using u16 = unsigned short;
using u32 = unsigned int;
typedef __attribute__((ext_vector_type(8))) short short8;
typedef __attribute__((ext_vector_type(4))) short s16x4;
typedef __attribute__((ext_vector_type(4))) float f32x4;
typedef __attribute__((ext_vector_type(2))) float f32x2;
typedef __attribute__((ext_vector_type(4))) u16 u16x4;
typedef __attribute__((ext_vector_type(4))) u32 u32x4;

constexpr int CB   = 4;
constexpr int CC   = 192;    // dim
constexpr int CN   = 16384;  // tokens per batch (128*128)
constexpr int BN   = CB * CN;
constexpr int CMLP = 384;

__device__ __forceinline__ float b2f(u16 u){ return __uint_as_float(((u32)u) << 16); }
__device__ __forceinline__ u16 f2b(float f){
  u32 u = __float_as_uint(f);
  u32 r = (u + 0x7FFFu + ((u >> 16) & 1u)) >> 16;
  return (u16)r;
}
// 8-byte-aligned load of 8 bf16
__device__ __forceinline__ short8 ld8(const u16* p) {
  s16x4 a = *(const s16x4*)p;
  s16x4 b = *(const s16x4*)(p + 4);
  short8 r;
  r[0]=a[0]; r[1]=a[1]; r[2]=a[2]; r[3]=a[3];
  r[4]=b[0]; r[5]=b[1]; r[6]=b[2]; r[7]=b[3];
  return r;
}
__device__ __forceinline__ u32 pk_bf16(float lo, float hi) {
  u32 r;
  asm("v_cvt_pk_bf16_f32 %0, %1, %2" : "=v"(r) : "v"(lo), "v"(hi));
  return r;
}
__device__ __forceinline__ float exp2_fast(float x) {
  float r;
  asm("v_exp_f32 %0, %1" : "=v"(r) : "v"(x));
  return r;
}
// async global -> LDS, 16 bytes/lane; LDS dest = wave-uniform base + lane*16
__device__ __forceinline__ void gl_lds16(const u16* g, u16* l) {
  __builtin_amdgcn_global_load_lds(
      (const __attribute__((address_space(1))) void*)(const void*)g,
      (__attribute__((address_space(3))) void*)(void*)l, 16, 0, 0);
}

// ---------------- LN (token-wise over C=192), src (B,C,N) f32 -> bf16 rows + fused
// cluster assignment (scores vs msnT + tie-exact argmax).
__global__ __launch_bounds__(256) void ln_k(const float* __restrict__ src,
    const float* __restrict__ gg, const float* __restrict__ bb, u16* __restrict__ out,
    const u16* __restrict__ msnT, int* __restrict__ belong)
{
  __shared__ float t[64 * 193];
  __shared__ float sg[192], sb[192];
  __shared__ float smu[64], srs[64];
  const int tid = threadIdx.x;
  const int blk = blockIdx.x;
  const int b = blk >> 8;
  const int n0 = (blk & 255) * 64;
  if (tid < 192) { sg[tid] = gg[tid]; sb[tid] = bb[tid]; }
  const size_t sbase = ((size_t)b * CC) * CN + n0;
  #pragma unroll
  for (int it = 0; it < 48; ++it) {
    int c = it * 4 + (tid >> 6);
    int tok = tid & 63;
    t[tok * 193 + c] = src[sbase + (size_t)c * CN + tok];
  }
  __syncthreads();
  {
    int tok = tid >> 2, sub = tid & 3;
    float s = 0.f, sq = 0.f;
    #pragma unroll
    for (int i = 0; i < 48; ++i) {
      float v = t[tok * 193 + sub * 48 + i];
      s += v; sq += v * v;
    }
    s  += __shfl_xor(s, 1);  s  += __shfl_xor(s, 2);
    sq += __shfl_xor(sq, 1); sq += __shfl_xor(sq, 2);
    float mu = s * (1.f / 192.f);
    float var = fmaxf(sq * (1.f / 192.f) - mu * mu, 0.f);
    float rs = rsqrtf(var + 1e-5f);
    if (sub == 0) { smu[tok] = mu; srs[tok] = rs; }
  }
  __syncthreads();
  const size_t obase = ((size_t)(b * CN + n0)) * CC;
  #pragma unroll
  for (int it = 0; it < 48; ++it) {
    int e = it * 256 + tid;
    int tk = e / 192, c = e % 192;
    float v = (t[tk * 193 + c] - smu[tk]) * srs[tk] * sg[c] + sb[c];
    out[obase + (size_t)tk * CC + c] = f2b(v);
  }

  {
    const int wv = tid >> 6, lane = tid & 63;
    const int l15 = lane & 15, g4 = lane >> 4, q8 = g4 * 8;
    const int tok = wv * 16 + l15;
    const float mu = smu[tok], rs = srs[tok];
    short8 afm[6];
    #pragma unroll
    for (int ks = 0; ks < 6; ++ks) {
      u32x4 qq;
      #pragma unroll
      for (int j = 0; j < 4; ++j) {
        int c = ks * 32 + q8 + 2 * j;
        float v0 = (t[tok * 193 + c]     - mu) * rs * sg[c]     + sb[c];
        float v1 = (t[tok * 193 + c + 1] - mu) * rs * sg[c + 1] + sb[c + 1];
        qq[j] = pk_bf16(v0, v1);
      }
      afm[ks] = __builtin_bit_cast(short8, qq);
    }
    f32x4 sacc[4];
    #pragma unroll
    for (int ct = 0; ct < 4; ++ct) {
      sacc[ct] = 0.f;
      const u16* pM = msnT + (ct * 16 + l15) * 192 + q8;
      short8 mf[6];
      #pragma unroll
      for (int ks = 0; ks < 6; ++ks) mf[ks] = *(const short8*)(pM + ks * 32);
      #pragma unroll
      for (int ks = 0; ks < 6; ++ks)
        sacc[ct] = __builtin_amdgcn_mfma_f32_16x16x32_bf16(afm[ks], mf[ks], sacc[ct], 0, 0, 0);
    }
    #pragma unroll
    for (int r = 0; r < 4; ++r) {
      float bv = -3e38f; int bi = 1 << 30;
      #pragma unroll
      for (int ct = 0; ct < 4; ++ct) {
        float v = sacc[ct][r];
        int ci = ct * 16 + l15;
        if (v > bv || (v == bv && ci < bi)) { bv = v; bi = ci; }
      }
      #pragma unroll
      for (int d = 1; d < 16; d <<= 1) {
        float ov = __shfl_xor(bv, d);
        int   oi = __shfl_xor(bi, d);
        if (ov > bv || (ov == bv && oi < bi)) { bv = ov; bi = oi; }
      }
      if (l15 == 0) belong[b * CN + n0 + wv * 16 + g4 * 4 + r] = bi;
    }
  }
}

// ---------------- QKV GEMM: block = 64 rows x 576 cols, af[4][6] per wave (4:1 W reuse).
// Q columns (col < 192) are pre-scaled by QSC = 24^-0.5 * log2(e): the attn kernel
// then consumes Q fragments raw (Q slice is overwritten by O afterwards anyway).
__global__ __launch_bounds__(256) void gemmQ_k(const u16* __restrict__ A,
    const u16* __restrict__ Wt, u16* __restrict__ qkv)
{
  __shared__ __attribute__((aligned(16))) u16 lA[64 * 192];
  const float QSC = 0.20412414523193154f * 1.4426950408889634f;
  const int tid = threadIdx.x;
  const int row0 = blockIdx.x * 64;
  const int wv = tid >> 6, lane = tid & 63;
  const int l15 = lane & 15, g4 = lane >> 4, q8 = g4 * 8;
  const int colw = wv * 144;

  #pragma unroll
  for (int j = 0; j < 6; ++j) {
    int C = (wv * 6 + j) * 64 + lane;
    int r = C / 24;
    int c = C - r * 24;
    gl_lds16(A + (size_t)(row0 + r) * 192 + c * 8, lA + (wv * 6 + j) * 512);
  }
  __syncthreads();
  short8 af[4][6];
  #pragma unroll
  for (int rt = 0; rt < 4; ++rt)
    #pragma unroll
    for (int ks = 0; ks < 6; ++ks)
      af[rt][ks] = *(const short8*)(lA + (rt * 16 + l15) * 192 + ks * 32 + q8);

  #pragma unroll
  for (int jc = 0; jc < 9; ++jc) {
    const u16* pW = Wt + (size_t)(colw + jc * 16 + l15) * 192 + q8;
    short8 wf[6];
    #pragma unroll
    for (int ks = 0; ks < 6; ++ks) wf[ks] = *(const short8*)(pW + ks * 32);
    f32x4 acc[4];
    #pragma unroll
    for (int rt = 0; rt < 4; ++rt) acc[rt] = 0.f;
    #pragma unroll
    for (int ks = 0; ks < 6; ++ks)
      #pragma unroll
      for (int rt = 0; rt < 4; ++rt)
        acc[rt] = __builtin_amdgcn_mfma_f32_16x16x32_bf16(af[rt][ks], wf[ks], acc[rt], 0, 0, 0);
    int col = colw + jc * 16 + l15;
    const float sc = (colw + jc * 16 < 192) ? QSC : 1.f;   // Q columns pre-scaled
    #pragma unroll
    for (int rt = 0; rt < 4; ++rt) {
      int row = row0 + rt * 16 + g4 * 4;
      #pragma unroll
      for (int r = 0; r < 4; ++r)
        qkv[(size_t)(row + r) * 576 + col] = f2b(acc[rt][r] * sc);
    }
  }
}

// ---------------- prep: normalized means (bf16, [64][192]) + kg/vg ([h][64][24] f32)
__global__ __launch_bounds__(192) void prep_means_k(const float* __restrict__ means,
    const float* __restrict__ Wkg, const float* __restrict__ Wvg,
    u16* __restrict__ msnT, float* __restrict__ kg, float* __restrict__ vg)
{
  __shared__ float sv[192];
  __shared__ float red[192];
  const int m = blockIdx.x, c = threadIdx.x;
  float v = means[m * 192 + c];
  sv[c] = v; red[c] = v * v;
  __syncthreads();
  for (int s = 96; s >= 3; s >>= 1) {
    if (c < s) red[c] += red[c + s];
    __syncthreads();
  }
  if (c == 0) red[0] = 1.f / (sqrtf(red[0] + red[1] + red[2]) + 1e-12f);
  __syncthreads();
  float scale = red[0];
  msnT[m * 192 + c] = f2b(v * scale);
  float a1 = 0.f, a2 = 0.f;
  for (int cc = 0; cc < 192; ++cc) {
    float mv = sv[cc];
    a1 += mv * Wkg[cc * 192 + c];
    a2 += mv * Wvg[cc * 192 + c];
  }
  int h = c / 24, d = c % 24;
  kg[h * (64 * 24) + m * 24 + d] = a1;
  vg[h * (64 * 24) + m * 24 + d] = a2;
}

// ---------------- merged weight prep
__global__ __launch_bounds__(256) void wprep_k(
    const float* __restrict__ Wp, const float* __restrict__ Wc, u16* __restrict__ WpcT,
    const float* __restrict__ Wq, const float* __restrict__ Wk, const float* __restrict__ Wv,
    u16* __restrict__ WqkvT,
    const float* __restrict__ Wfc1, u16* __restrict__ Wfc1T,
    const float* __restrict__ Wfc2, u16* __restrict__ Wfc2T)
{
  int blk = blockIdx.x;
  int tid = threadIdx.x;
  if (blk < 144) {
    int e = blk * 256 + tid;
    if (e < 192 * 192) {
      int i = e / 192, j = e % 192;
      float a = 0.f;
      for (int k = 0; k < 192; ++k) a += Wp[i * 192 + k] * Wc[k * 192 + j];
      WpcT[j * 192 + i] = f2b(a);
    }
    return;
  }
  blk -= 144;
  if (blk < 432) {
    int which = blk / 144;
    int e = (blk % 144) * 256 + tid;
    const float* W = (which == 0) ? Wq : (which == 1) ? Wk : Wv;
    if (e < 192 * 192) {
      int j = e / 192, k = e % 192;
      WqkvT[which * 192 * 192 + e] = f2b(W[k * 192 + j]);
    }
    return;
  }
  blk -= 432;
  if (blk < 288) {
    int e = blk * 256 + tid;
    if (e < 192 * 384) {
      int j = e / 192, k = e % 192;
      Wfc1T[e] = f2b(Wfc1[k * 384 + j]);
    }
    return;
  }
  blk -= 288;
  {
    int e = blk * 256 + tid;
    if (e < 384 * 192) {
      int j = e / 384, k = e % 384;
      Wfc2T[e] = f2b(Wfc2[k * 192 + j]);
    }
  }
}

// ---------------- fused RESID(proj+residual) + MLP-LN + fc1 GEMM.
__global__ __launch_bounds__(256) void resid_k(const u16* __restrict__ qkv,
    const u16* __restrict__ WpcT, const float* __restrict__ x, u16* __restrict__ xt2,
    const float* __restrict__ g2, const float* __restrict__ b2,
    const u16* __restrict__ Wfc1T, u16* __restrict__ h1)
{
  __shared__ __attribute__((aligned(16))) u16 shraw[64 * 200];  // lA alias lnb16
  __shared__ float smu2[64], srs2[64];
  u16* lA    = shraw;
  u16* lnb16 = shraw;
  const int tid = threadIdx.x;
  const int row0 = blockIdx.x * 64;
  const int b = row0 >> 14;
  const int wv = tid >> 6, lane = tid & 63;
  const int l15 = lane & 15, g4 = lane >> 4, q8 = g4 * 8;

  #pragma unroll
  for (int j = 0; j < 6; ++j) {
    int C = (wv * 6 + j) * 64 + lane;
    int r = C / 24;
    int c = C - r * 24;
    const u16* gp = qkv + (size_t)(row0 + r) * 576 + c * 8;
    gl_lds16(gp, lA + (wv * 6 + j) * 512);
  }
  __syncthreads();
  short8 af[4][6];
  #pragma unroll
  for (int rt = 0; rt < 4; ++rt)
    #pragma unroll
    for (int ks = 0; ks < 6; ++ks)
      af[rt][ks] = *(const short8*)(lA + (rt * 16 + l15) * 192 + ks * 32 + q8);
  __syncthreads();

  const int colw = wv * 48;
  #pragma unroll
  for (int jc = 0; jc < 3; ++jc) {
    const u16* pW = WpcT + (size_t)(colw + jc * 16 + l15) * 192 + q8;
    short8 wf[6];
    #pragma unroll
    for (int ks = 0; ks < 6; ++ks) wf[ks] = *(const short8*)(pW + ks * 32);
    f32x4 acc[4];
    #pragma unroll
    for (int rt = 0; rt < 4; ++rt) acc[rt] = 0.f;
    #pragma unroll
    for (int ks = 0; ks < 6; ++ks)
      #pragma unroll
      for (int rt = 0; rt < 4; ++rt)
        acc[rt] = __builtin_amdgcn_mfma_f32_16x16x32_bf16(wf[ks], af[rt][ks], acc[rt], 0, 0, 0);
    #pragma unroll
    for (int rt = 0; rt < 4; ++rt) {
      int n = ((row0 + rt * 16) & 16383) + l15;
      #pragma unroll
      for (int r = 0; r < 4; ++r) {
        int col = colw + jc * 16 + g4 * 4 + r;
        size_t o2 = ((size_t)(b * CC + col)) * CN + n;
        float val = x[o2] + acc[rt][r];
        u16 vb = f2b(val);
        xt2[o2] = vb;
        lnb16[(rt * 16 + l15) * 200 + col] = vb;
      }
    }
  }
  __syncthreads();

  {
    int tok = tid >> 2, sub = tid & 3;
    float s = 0.f, sq = 0.f;
    #pragma unroll
    for (int i = 0; i < 48; ++i) {
      float v = b2f(lnb16[tok * 200 + sub * 48 + i]);
      s += v; sq += v * v;
    }
    s  += __shfl_xor(s, 1);  s  += __shfl_xor(s, 2);
    sq += __shfl_xor(sq, 1); sq += __shfl_xor(sq, 2);
    float mu = s * (1.f / 192.f);
    float var = fmaxf(sq * (1.f / 192.f) - mu * mu, 0.f);
    float rs = rsqrtf(var + 1e-5f);
    if (sub == 0) { smu2[tok] = mu; srs2[tok] = rs; }
  }
  __syncthreads();
  #pragma unroll
  for (int it = 0; it < 48; ++it) {
    int e = it * 256 + tid;
    int tk = e / 192, c = e % 192;
    float v = (b2f(lnb16[tk * 200 + c]) - smu2[tk]) * srs2[tk] * g2[c] + b2[c];
    lnb16[tk * 200 + c] = f2b(v);
  }
  __syncthreads();

  short8 af2[4][6];
  #pragma unroll
  for (int rt = 0; rt < 4; ++rt)
    #pragma unroll
    for (int ks = 0; ks < 6; ++ks)
      af2[rt][ks] = *(const short8*)(lnb16 + (rt * 16 + l15) * 200 + ks * 32 + q8);
  const int colw2 = wv * 96;
  #pragma unroll
  for (int jc = 0; jc < 6; ++jc) {
    const u16* pW = Wfc1T + (size_t)(colw2 + jc * 16 + l15) * 192 + q8;
    short8 wf[6];
    #pragma unroll
    for (int ks = 0; ks < 6; ++ks) wf[ks] = *(const short8*)(pW + ks * 32);
    f32x4 acc[4];
    #pragma unroll
    for (int rt = 0; rt < 4; ++rt) acc[rt] = 0.f;
    #pragma unroll
    for (int ks = 0; ks < 6; ++ks)
      #pragma unroll
      for (int rt = 0; rt < 4; ++rt)
        acc[rt] = __builtin_amdgcn_mfma_f32_16x16x32_bf16(af2[rt][ks], wf[ks], acc[rt], 0, 0, 0);
    int col = colw2 + jc * 16 + l15;
    #pragma unroll
    for (int rt = 0; rt < 4; ++rt) {
      int row = row0 + rt * 16 + g4 * 4;
      #pragma unroll
      for (int r = 0; r < 4; ++r)
        h1[(size_t)(row + r) * CMLP + col] = f2b(acc[rt][r]);
    }
  }
}

// ---------------- FINAL GEMM: h2g rows -> out (B,C,N) f32 + xt2 resid.
template<int KTOT, int NCOLS>
__global__ __launch_bounds__(256) void gemmF_k(const u16* __restrict__ A,
    const u16* __restrict__ Wt, const u16* __restrict__ resid,
    float* __restrict__ o, int astride)
{
  __shared__ __attribute__((aligned(16))) u16 lA[64 * 192];
  constexpr int KC = KTOT / 192;
  constexpr int WCOLS = NCOLS / 4;
  constexpr int WCT = WCOLS / 16;
  const int tid = threadIdx.x;
  const int row0 = blockIdx.x * 64;
  const int b = row0 >> 14;
  const int wv = tid >> 6, lane = tid & 63;
  const int l15 = lane & 15, g4 = lane >> 4, q8 = g4 * 8;
  const int colw = wv * WCOLS;

  f32x4 acc[WCT * 4];
  #pragma unroll
  for (int i = 0; i < WCT * 4; ++i) acc[i] = 0.f;

  #pragma unroll
  for (int kc = 0; kc < KC; ++kc) {
    if (kc) __syncthreads();
    #pragma unroll
    for (int j = 0; j < 6; ++j) {
      int C = (wv * 6 + j) * 64 + lane;
      int r = C / 24;
      int c = C - r * 24;
      const u16* gp = A + (size_t)(row0 + r) * astride + kc * 192 + c * 8;
      gl_lds16(gp, lA + (wv * 6 + j) * 512);
    }
    __syncthreads();
    short8 af[4][6];
    #pragma unroll
    for (int rt = 0; rt < 4; ++rt)
      #pragma unroll
      for (int ks = 0; ks < 6; ++ks)
        af[rt][ks] = *(const short8*)(lA + (rt * 16 + l15) * 192 + ks * 32 + q8);

    #pragma unroll
    for (int jc = 0; jc < WCT; ++jc) {
      const u16* pW = Wt + (size_t)(colw + jc * 16 + l15) * KTOT + kc * 192 + q8;
      short8 wf[6];
      #pragma unroll
      for (int ks = 0; ks < 6; ++ks) wf[ks] = *(const short8*)(pW + ks * 32);
      #pragma unroll
      for (int ks = 0; ks < 6; ++ks)
        #pragma unroll
        for (int rt = 0; rt < 4; ++rt)
          acc[jc * 4 + rt] = __builtin_amdgcn_mfma_f32_16x16x32_bf16(wf[ks], af[rt][ks], acc[jc * 4 + rt], 0, 0, 0);
    }
  }
  #pragma unroll
  for (int jc = 0; jc < WCT; ++jc)
    #pragma unroll
    for (int tt = 0; tt < 4; ++tt) {
      int n = ((row0 + tt * 16) & 16383) + l15;
      #pragma unroll
      for (int r = 0; r < 4; ++r) {
        int outcol = colw + jc * 16 + g4 * 4 + r;
        size_t o2 = ((size_t)(b * CC + outcol)) * CN + n;
        o[o2] = b2f(resid[o2]) + acc[jc * 4 + tt][r];
      }
    }
}

// ---------------- stable counting sort: hist -> scan -> rank/scatter (idx only)
__global__ __launch_bounds__(256) void hist_k(const int* __restrict__ belong, int* __restrict__ histG)
{
  __shared__ int h[64];
  int tid = threadIdx.x, blk = blockIdx.x;
  if (tid < 64) h[tid] = 0;
  __syncthreads();
  int c = belong[blk * 256 + tid];
  atomicAdd(&h[c], 1);
  __syncthreads();
  if (tid < 64) histG[blk * 64 + tid] = h[tid];
}

__global__ __launch_bounds__(64) void scan_k(const int* __restrict__ histG, int* __restrict__ chunkBase)
{
  int b = blockIdx.x, c = threadIdx.x;
  int tot = 0;
  for (int ch = 0; ch < 64; ++ch) tot += histG[(b * 64 + ch) * 64 + c];
  int inc = tot;
  for (int d = 1; d < 64; d <<= 1) {
    int v = __shfl_up(inc, d);
    if (c >= d) inc += v;
  }
  int run = inc - tot;
  for (int ch = 0; ch < 64; ++ch) {
    chunkBase[(b * 64 + ch) * 64 + c] = run;
    run += histG[(b * 64 + ch) * 64 + c];
  }
}

__global__ __launch_bounds__(256) void rank_k(const int* __restrict__ belong,
    const int* __restrict__ chunkBase, int* __restrict__ idx)
{
  __shared__ int WH[4][64];
  int tid = threadIdx.x, blk = blockIdx.x;
  int b = blk >> 6, chl = blk & 63;
  int wv = tid >> 6, lane = tid & 63;
  ((int*)WH)[tid] = 0;
  __syncthreads();
  int nl = chl * 256 + tid;
  int c = belong[blk * 256 + tid];
  int rank = 0;
  for (int m = 0; m < 64; ++m) {
    unsigned long long msk = __ballot(c == m);
    if (c == m) {
      rank = __popcll(msk & ((1ull << lane) - 1ull));
      if (rank == 0) WH[wv][m] = __popcll(msk);
    }
  }
  __syncthreads();
  int off = 0;
  #pragma unroll
  for (int w = 0; w < 3; ++w) if (w < wv) off += WH[w][c];
  int pos = chunkBase[(b * 64 + chl) * 64 + c] + off + rank;
  idx[b * CN + pos] = nl;
}

// ---------------- MFMA flash attention: no-max softmax, shuffle P-transfer, ones-row
// denominator, setprio. Q arrives pre-scaled by QSC (gemmQ epilogue) -> raw ld8 frags.
// Window-K rows staged via global_load_lds (sK is linear [320][24]); dict rows converted.
// Grid (g,h,b): same-row sharers 0 mod 8 -> same XCD L2.
__global__ __launch_bounds__(256) void attn_k(u16* __restrict__ qkv,
    const float* __restrict__ kg, const float* __restrict__ vg,
    const int* __restrict__ idx)
{
  __shared__ __attribute__((aligned(16))) u16 sK[320 * 24];
  __shared__ __attribute__((aligned(16))) u16 sVT[25 * 332];  // row 24 = ones
  __shared__ u16 sidx[256];
  const int g = blockIdx.x, h = blockIdx.y, b = blockIdx.z;
  const int tid = threadIdx.x;
  const int wave = tid >> 6, lane = tid & 63;
  const int l15 = lane & 15, g4 = lane >> 4;
  const int q8 = g4 * 8;
  const size_t base = (size_t)b * CN * 576;
  short8 z8 = {0,0,0,0,0,0,0,0};

  {
    int p = g * 128 + tid;
    if (p >= CN) p = 2 * CN - 1 - p;
    sidx[tid] = (u16)idx[b * CN + p];
  }
  for (int e = tid; e < 332; e += 256) sVT[24 * 332 + e] = 0x3F80;
  __syncthreads();

  // window K rows 0..255 via DMA: 256 rows x 48B = 768 x 16B chunks = 3 x 256 threads
  #pragma unroll
  for (int it = 0; it < 3; ++it) {
    int C = (it * 4 + wave) * 64 + lane;   // chunk id 0..767
    int r = C / 3, cs = C - r * 3;
    int p = sidx[r];
    gl_lds16(qkv + base + (size_t)p * 576 + 192 + h * 24 + cs * 8,
             sK + (it * 4 + wave) * 512);
  }
  // dict K rows 256..319 (f32 -> bf16 convert)
  #pragma unroll
  for (int it = 0; it < 2; ++it) {
    int e4 = (it * 256 + tid) * 4;
    if (e4 < 1536) {
      int r = e4 / 24, c = e4 % 24;
      const float* kp = kg + h * 1536 + r * 24 + c;
      u16x4 o;
      o[0] = f2b(kp[0]); o[1] = f2b(kp[1]); o[2] = f2b(kp[2]); o[3] = f2b(kp[3]);
      *(u16x4*)(sK + (256 + r) * 24 + c) = o;
    }
  }
  // V^T staging (transposed writes; cannot DMA)
  #pragma unroll
  for (int it = 0; it < 8; ++it) {
    int e4 = (it * 256 + tid) * 4;
    if (e4 < 7680) {
      int kk = e4 / 24, c = e4 % 24;
      if (kk < 256) {
        int p = sidx[kk];
        u16x4 v = *(const u16x4*)(qkv + base + (size_t)p * 576 + 384 + h * 24 + c);
        sVT[(c + 0) * 332 + kk] = v[0];
        sVT[(c + 1) * 332 + kk] = v[1];
        sVT[(c + 2) * 332 + kk] = v[2];
        sVT[(c + 3) * 332 + kk] = v[3];
      } else {
        const float* vp = vg + h * 1536 + (kk - 256) * 24 + c;
        sVT[(c + 0) * 332 + kk] = f2b(vp[0]);
        sVT[(c + 1) * 332 + kk] = f2b(vp[1]);
        sVT[(c + 2) * 332 + kk] = f2b(vp[2]);
        sVT[(c + 3) * 332 + kk] = f2b(vp[3]);
      }
    }
  }

  // Q B-frags raw (pre-scaled in gemmQ)
  short8 qf[2];
  #pragma unroll
  for (int rt = 0; rt < 2; ++rt) {
    int qrow = sidx[wave * 32 + rt * 16 + l15];
    qf[rt] = (g4 < 3) ? ld8(qkv + base + (size_t)qrow * 576 + h * 24 + q8) : z8;
  }
  __syncthreads();

  f32x4 O1[2][2], O2[2][2];
  #pragma unroll
  for (int rt = 0; rt < 2; ++rt)
    #pragma unroll
    for (int ct2 = 0; ct2 < 2; ++ct2) { O1[rt][ct2] = 0.f; O2[rt][ct2] = 0.f; }

  const int srcLo = ((lane & 16) << 1) + l15;
  const int srcHi = srcLo + 16;
  const bool hiSel = lane >= 32;
  f32x4 zz = 0.f;

  auto do_tile = [&](int ktile, f32x4 (*O)[2]) {
    short8 aK[4];
    #pragma unroll
    for (int ct = 0; ct < 4; ++ct)
      aK[ct] = (g4 < 3) ? ld8(sK + (ktile + ct * 16 + l15) * 24 + q8) : z8;
    short8 bV[2][2];
    #pragma unroll
    for (int kc = 0; kc < 2; ++kc)
      #pragma unroll
      for (int ct2 = 0; ct2 < 2; ++ct2) {
        int vrow = ct2 * 16 + l15;
        bV[kc][ct2] = (vrow < 25) ? ld8(sVT + vrow * 332 + ktile + kc * 32 + q8) : z8;
      }
    #pragma unroll
    for (int rt = 0; rt < 2; ++rt) {
      f32x4 p[4];
      __builtin_amdgcn_s_setprio(1);
      #pragma unroll
      for (int ct = 0; ct < 4; ++ct)
        p[ct] = __builtin_amdgcn_mfma_f32_16x16x32_bf16(aK[ct], qf[rt], zz, 0, 0, 0);
      __builtin_amdgcn_s_setprio(0);
      #pragma unroll
      for (int ct = 0; ct < 4; ++ct)
        #pragma unroll
        for (int r = 0; r < 4; ++r)
          p[ct][r] = exp2_fast(p[ct][r]);
      #pragma unroll
      for (int kc = 0; kc < 2; ++kc) {
        u32 wA0 = pk_bf16(p[kc * 2][0], p[kc * 2][1]);
        u32 wA1 = pk_bf16(p[kc * 2][2], p[kc * 2][3]);
        u32 wB0 = pk_bf16(p[kc * 2 + 1][0], p[kc * 2 + 1][1]);
        u32 wB1 = pk_bf16(p[kc * 2 + 1][2], p[kc * 2 + 1][3]);
        u32 a0 = (u32)__shfl((int)wA0, srcLo), a1 = (u32)__shfl((int)wA1, srcLo);
        u32 a2 = (u32)__shfl((int)wA0, srcHi), a3 = (u32)__shfl((int)wA1, srcHi);
        u32 b0 = (u32)__shfl((int)wB0, srcLo), b1 = (u32)__shfl((int)wB1, srcLo);
        u32 b2 = (u32)__shfl((int)wB0, srcHi), b3 = (u32)__shfl((int)wB1, srcHi);
        u32x4 fr;
        fr[0] = hiSel ? b0 : a0; fr[1] = hiSel ? b1 : a1;
        fr[2] = hiSel ? b2 : a2; fr[3] = hiSel ? b3 : a3;
        short8 aP = __builtin_bit_cast(short8, fr);
        __builtin_amdgcn_s_setprio(1);
        #pragma unroll
        for (int ct2 = 0; ct2 < 2; ++ct2)
          O[rt][ct2] = __builtin_amdgcn_mfma_f32_16x16x32_bf16(aP, bV[kc][ct2], O[rt][ct2], 0, 0, 0);
        __builtin_amdgcn_s_setprio(0);
      }
    }
  };

  do_tile(0,   O1);
  do_tile(64,  O1);
  do_tile(128, O1);
  do_tile(192, O1);
  do_tile(256, O2);

  const int lsrc = (lane & 48) + 8;
  #pragma unroll
  for (int rt = 0; rt < 2; ++rt) {
    #pragma unroll
    for (int r = 0; r < 4; ++r) {
      float s1 = __shfl(O1[rt][1][r], lsrc);
      float s2 = __shfl(O2[rt][1][r], lsrc);
      float i1 = 1.f / s1;
      float i2 = 1.f / s2;
      int tok = sidx[wave * 32 + rt * 16 + g4 * 4 + r];
      #pragma unroll
      for (int ct2 = 0; ct2 < 2; ++ct2) {
        int d = ct2 * 16 + l15;
        if (d < 24) {
          float v = O1[rt][ct2][r] * i1 + O2[rt][ct2][r] * i2;
          qkv[base + (size_t)tok * 576 + h * 24 + d] = f2b(v);
        }
      }
    }
  }
}

// ---------------- depthwise 3x3 + GELU, token-major (B,N,384), 8 channels per block.
__global__ __launch_bounds__(256) void conv_k(const u16* __restrict__ h1,
    const float* __restrict__ dw, u16* __restrict__ h2g)
{
  __shared__ float t[1156 * 10];
  __shared__ float sdw[72];
  const int tile = blockIdx.x;
  const int jg = blockIdx.y;
  const int bb = blockIdx.z;
  const int y0 = (tile >> 2) * 32, x0 = (tile & 3) * 32;
  const int tid = threadIdx.x;
  if (tid < 72) sdw[tid] = dw[jg * 72 + tid];
  #pragma unroll
  for (int it = 0; it < 5; ++it) {
    int e = it * 256 + tid;
    if (e < 1156) {
      int yy = e / 34 - 1 + y0, xx = e % 34 - 1 + x0;
      float v[8];
      if (yy >= 0 && yy < 128 && xx >= 0 && xx < 128) {
        short8 raw = *(const short8*)(h1 + ((size_t)(bb * CN + yy * 128 + xx)) * CMLP + jg * 8);
        #pragma unroll
        for (int c = 0; c < 8; ++c) v[c] = b2f((u16)raw[c]);
      } else {
        #pragma unroll
        for (int c = 0; c < 8; ++c) v[c] = 0.f;
      }
      #pragma unroll
      for (int c = 0; c < 8; c += 2) {
        f32x2 p; p[0] = v[c]; p[1] = v[c + 1];
        *(f32x2*)(t + e * 10 + c) = p;
      }
    }
  }
  __syncthreads();
  float acc[4][8];
  #pragma unroll
  for (int px = 0; px < 4; ++px)
    #pragma unroll
    for (int c = 0; c < 8; ++c) acc[px][c] = 0.f;
  #pragma unroll
  for (int k = 0; k < 9; ++k) {
    const int dy = k / 3, dx = k % 3;
    float w[8];
    #pragma unroll
    for (int c = 0; c < 8; ++c) w[c] = sdw[c * 9 + k];
    #pragma unroll
    for (int px = 0; px < 4; ++px) {
      int idx2 = px * 256 + tid;
      int oy = idx2 >> 5, ox = idx2 & 31;
      const float* vp = t + ((oy + dy) * 34 + ox + dx) * 10;
      #pragma unroll
      for (int c = 0; c < 8; ++c) acc[px][c] += vp[c] * w[c];
    }
  }
  #pragma unroll
  for (int px = 0; px < 4; ++px) {
    int idx2 = px * 256 + tid;
    int oy = idx2 >> 5, ox = idx2 & 31;
    short8 o;
    #pragma unroll
    for (int c = 0; c < 8; ++c) {
      float a = acc[px][c];
      float u = 1.5957691216057308f * (a + 0.044715f * a * a * a);
      float gel = a / (1.f + __expf(-u));
      o[c] = (short)f2b(gel);
    }
    *(short8*)(h2g + ((size_t)(bb * CN + (y0 + oy) * 128 + x0 + ox)) * CMLP + jg * 8) = o;
  }
}

extern "C" void kernel_launch(void* const* d_in, const int* in_sizes, int n_in,
                              void* d_out, int out_size, void* d_ws, size_t ws_size,
                              hipStream_t stream)
{
  const float* x     = (const float*)d_in[0];
  const float* ln_g  = (const float*)d_in[1];
  const float* ln_b  = (const float*)d_in[2];
  const float* Wq    = (const float*)d_in[3];
  const float* Wk    = (const float*)d_in[4];
  const float* Wv    = (const float*)d_in[5];
  const float* Wproj = (const float*)d_in[6];
  const float* Wkg   = (const float*)d_in[7];
  const float* Wvg   = (const float*)d_in[8];
  const float* means = (const float*)d_in[9];
  const float* Wconv = (const float*)d_in[10];
  const float* mlp_g = (const float*)d_in[11];
  const float* mlp_b = (const float*)d_in[12];
  const float* Wfc1  = (const float*)d_in[13];
  const float* dw    = (const float*)d_in[14];
  const float* Wfc2  = (const float*)d_in[15];
  float* out = (float*)d_out;
  (void)in_sizes; (void)n_in; (void)out_size; (void)ws_size;

  char* ws = (char*)d_ws;
  size_t off = 0;
  auto alloc = [&](size_t sz) { void* p = ws + off; off += (sz + 255) & ~(size_t)255; return p; };
  u16*  xn    = (u16*)alloc((size_t)BN * 192 * 2);
  u16*  qkv   = (u16*)alloc((size_t)BN * 576 * 2);
  u16*  xt2   = (u16*)alloc((size_t)BN * 192 * 2);   // channel-major (B,C,N) bf16
  u16*  h1    = (u16*)alloc((size_t)BN * 384 * 2);   // (B,N,384)
  u16*  h2g   = (u16*)alloc((size_t)BN * 384 * 2);   // (B,N,384)
  u16*  msnT  = (u16*)alloc(64 * 192 * 2);
  u16*  WqkvT = (u16*)alloc(576 * 192 * 2);
  u16*  WpcT  = (u16*)alloc(192 * 192 * 2);
  u16*  Wfc1T = (u16*)alloc(384 * 192 * 2);
  u16*  Wfc2T = (u16*)alloc(192 * 384 * 2);
  float* kg   = (float*)alloc(8 * 64 * 24 * 4);
  float* vg   = (float*)alloc(8 * 64 * 24 * 4);
  int*  belong = (int*)alloc(BN * 4);
  int*  idxb   = (int*)alloc(BN * 4);
  int*  histG  = (int*)alloc(256 * 64 * 4);
  int*  chunkBase = (int*)alloc(256 * 64 * 4);

  prep_means_k<<<64, 192, 0, stream>>>(means, Wkg, Wvg, msnT, kg, vg);
  wprep_k<<<1152, 256, 0, stream>>>(Wproj, Wconv, WpcT, Wq, Wk, Wv, WqkvT,
                                    Wfc1, Wfc1T, Wfc2, Wfc2T);

  ln_k<<<1024, 256, 0, stream>>>(x, ln_g, ln_b, xn, msnT, belong);
  hist_k<<<256, 256, 0, stream>>>(belong, histG);
  scan_k<<<4, 64, 0, stream>>>(histG, chunkBase);
  rank_k<<<256, 256, 0, stream>>>(belong, chunkBase, idxb);
  gemmQ_k<<<1024, 256, 0, stream>>>(xn, WqkvT, qkv);
  attn_k<<<dim3(128, 8, 4), 256, 0, stream>>>(qkv, kg, vg, idxb);
  resid_k<<<1024, 256, 0, stream>>>(qkv, WpcT, x, xt2, mlp_g, mlp_b, Wfc1T, h1);
  conv_k<<<dim3(16, 48, 4), 256, 0, stream>>>(h1, dw, h2g);
  gemmF_k<384, 192><<<1024, 256, 0, stream>>>(h2g, Wfc2T, xt2, out, 384);
}